// Round 10
// baseline (169.032 us; speedup 1.0000x reference)
//
#include <hip/hip_runtime.h>

// KnowledgeEmbedding loss via bf16 MFMA GEMMs, two-phase:
//  1) ke_prep: gather each distinct row ONCE -> dense bf16 tables in d_ws
//     A-table [rel][4096][136]: ex = head[h]+rvec, k100 = bias[t], pad 0
//     B-table [rel][256][136]:  tail[neg],          k100 = 1.0,    pad 0
//  2) ke_main: R9 structure (64x128 tile, 16x16x32 bf16 MFMA, PITCH=136
//     conflict-free LDS, bias folded -> layout-agnostic softplus-sum, fused
//     pos term) but staging = contiguous 16B/lane copies from the tables.
// WHY: R5-R9 model: t = ~16us + scattered_gather_bytes/3.7 TB/s. R9 staged
// 78 MB scattered fp32 + cvt (2x redundant per row). Now scattered = 14 MB
// (prep, once); main streams 53 MB contiguous from L2/L3-resident tables.
// ws_size = 268 MB (observed poison fills) >> 9.5 MB needed.
// PITCH=136 shorts (68 words == 4 mod 32): frag reads & copy writes uniform
// 8 words/bank (R9: fixed 5.9M conflict cycles of PITCH=128).

#define EMBED   100
#define BATCH   4096
#define NUM_NEG 256
#define BM      64
#define BN      128
#define PITCH   136

typedef __attribute__((ext_vector_type(8))) short s8;
typedef __attribute__((ext_vector_type(4))) short s4;
typedef __attribute__((ext_vector_type(4))) float f4;

struct RelP {
    const float* head;
    const float* tail;
    const float* bias;
    int hc, tc;
};

struct Params {
    RelP rel[8];
    const float* rel_vecs;
    const int*   batch_idxs;
    const int*   neg_idxs;
    float*       out;
};

__device__ __forceinline__ float softplus_f(float x) {
    float e = __expf(-fabsf(x));
    return fmaxf(x, 0.0f) + __logf(1.0f + e);
}

__device__ __forceinline__ unsigned short bf16_rne(float f) {
    unsigned u = __float_as_uint(f);
    u += 0x7FFFu + ((u >> 16) & 1u);
    return (unsigned short)(u >> 16);
}

__device__ __forceinline__ float bf16_to_f(short s) {
    return __uint_as_float(((unsigned)(unsigned short)s) << 16);
}

// ---- phase 1: one thread per distinct row (32768 A + 2048 B = 136 blocks) ----
__launch_bounds__(256, 4)
__global__ void ke_prep(Params p, short* aws, short* bws) {
    const int id  = blockIdx.x * 256 + threadIdx.x;
    const bool isA = id < 32768;
    const int r = isA ? (id >> 12) : ((id - 32768) >> 8);
    const RelP rp = p.rel[r];

    const float* src;
    unsigned short extra;
    short* dst;
    if (isA) {
        const int row = id & 4095;
        const int h  = p.batch_idxs[row * 8 + rp.hc];
        const int ti = p.batch_idxs[row * 8 + rp.tc];
        src   = rp.head + (size_t)h * EMBED;
        extra = bf16_rne(rp.bias[ti]);
        dst   = aws + (size_t)id * PITCH;
    } else {
        const int j = id - 32768;
        const int n = p.neg_idxs[(j >> 8) * NUM_NEG + (j & 255)];
        src   = rp.tail + (size_t)n * EMBED;
        extra = 0x3F80;                   // bf16(1.0)
        dst   = bws + (size_t)j * PITCH;
    }

    const float4* s4p = (const float4*)src;
    const float4* rv4 = (const float4*)(p.rel_vecs + r * EMBED);

#pragma unroll
    for (int j = 0; j < 12; ++j) {
        float4 f0 = s4p[2 * j];
        float4 f1 = s4p[2 * j + 1];
        if (isA) {
            const float4 a = rv4[2 * j];
            const float4 b = rv4[2 * j + 1];
            f0.x += a.x; f0.y += a.y; f0.z += a.z; f0.w += a.w;
            f1.x += b.x; f1.y += b.y; f1.z += b.z; f1.w += b.w;
        }
        s8 v = { (short)bf16_rne(f0.x), (short)bf16_rne(f0.y),
                 (short)bf16_rne(f0.z), (short)bf16_rne(f0.w),
                 (short)bf16_rne(f1.x), (short)bf16_rne(f1.y),
                 (short)bf16_rne(f1.z), (short)bf16_rne(f1.w) };
        *(s8*)(dst + 8 * j) = v;
    }
    {   // floats 96..99
        float4 f = s4p[24];
        if (isA) {
            const float4 a = rv4[24];
            f.x += a.x; f.y += a.y; f.z += a.z; f.w += a.w;
        }
        s4 v = { (short)bf16_rne(f.x), (short)bf16_rne(f.y),
                 (short)bf16_rne(f.z), (short)bf16_rne(f.w) };
        *(s4*)(dst + 96) = v;
    }
    {   // k=100..103: extra,0,0,0 ; k=104..135: zeros
        s4 v = { (short)extra, 0, 0, 0 };
        *(s4*)(dst + 100) = v;
        s8 z = { 0,0,0,0,0,0,0,0 };
#pragma unroll
        for (int j = 0; j < 4; ++j)
            *(s8*)(dst + 104 + 8 * j) = z;
    }
}

// ---- phase 2: GEMM + softplus-sum; staging = contiguous copies ----
__launch_bounds__(256, 3)
__global__ void ke_main(Params p, const short* aws, const short* bws) {
    // grid: 8 rel * 64 rowblocks * 2 negblocks = 1024
    const int bid = blockIdx.x;
    const int r   = bid & 7;
    const int rb  = (bid >> 3) & 63;
    const int nb  = bid >> 9;
    const int tid = threadIdx.x;

    __shared__ __align__(16) short As[BM * PITCH];   // 17408 B
    __shared__ __align__(16) short Bs[BN * PITCH];   // 34816 B

    const RelP rp = p.rel[r];

    // A: 1088 s8-chunks; B: 2176 s8-chunks; all contiguous (16 B/lane).
    {
        const s8* asrc = (const s8*)(aws + (size_t)(r * 4096 + rb * BM) * PITCH);
        s8* adst = (s8*)As;
#pragma unroll
        for (int j = 0; j < 4; ++j)
            adst[tid + 256 * j] = asrc[tid + 256 * j];
        if (tid < 64) adst[1024 + tid] = asrc[1024 + tid];

        const s8* bsrc = (const s8*)(bws + (size_t)(r * NUM_NEG + nb * BN) * PITCH);
        s8* bdst = (s8*)Bs;
#pragma unroll
        for (int j = 0; j < 8; ++j)
            bdst[tid + 256 * j] = bsrc[tid + 256 * j];
        if (tid < 128) bdst[2048 + tid] = bsrc[2048 + tid];
    }

    // pos-term prep (loads issued before barrier)
    const bool doPos = (nb == 0) && (tid >= 192);
    const float* ptail = rp.tail;
    float pbias = 0.0f;
    if (doPos) {
        const int prow = rb * BM + (tid - 192);
        const int pt = p.batch_idxs[prow * 8 + rp.tc];
        ptail = rp.tail + (size_t)pt * EMBED;
        pbias = rp.bias[pt];
    }

    __syncthreads();

    // ---- MFMA: 4 waves, wave tile 32 rows x 64 negs ----
    const int wave = tid >> 6;
    const int lane = tid & 63;
    const int li   = lane & 15;
    const int q    = lane >> 4;
    const int wm   = wave & 1;
    const int wn   = wave >> 1;

    f4 acc[2][4];
#pragma unroll
    for (int i = 0; i < 2; ++i)
#pragma unroll
        for (int j = 0; j < 4; ++j)
            acc[i][j] = (f4){0.f, 0.f, 0.f, 0.f};

    const short* Abase = As + (wm * 32 + li) * PITCH + q * 8;
    const short* Bbase = Bs + (wn * 64 + li) * PITCH + q * 8;

#pragma unroll
    for (int s = 0; s < 4; ++s) {
        const s8 a0 = *(const s8*)(Abase +  0 * PITCH + s * 32);
        const s8 a1 = *(const s8*)(Abase + 16 * PITCH + s * 32);
        const s8 b0 = *(const s8*)(Bbase +  0 * PITCH + s * 32);
        const s8 b1 = *(const s8*)(Bbase + 16 * PITCH + s * 32);
        const s8 b2 = *(const s8*)(Bbase + 32 * PITCH + s * 32);
        const s8 b3 = *(const s8*)(Bbase + 48 * PITCH + s * 32);
        acc[0][0] = __builtin_amdgcn_mfma_f32_16x16x32_bf16(a0, b0, acc[0][0], 0, 0, 0);
        acc[0][1] = __builtin_amdgcn_mfma_f32_16x16x32_bf16(a0, b1, acc[0][1], 0, 0, 0);
        acc[0][2] = __builtin_amdgcn_mfma_f32_16x16x32_bf16(a0, b2, acc[0][2], 0, 0, 0);
        acc[0][3] = __builtin_amdgcn_mfma_f32_16x16x32_bf16(a0, b3, acc[0][3], 0, 0, 0);
        acc[1][0] = __builtin_amdgcn_mfma_f32_16x16x32_bf16(a1, b0, acc[1][0], 0, 0, 0);
        acc[1][1] = __builtin_amdgcn_mfma_f32_16x16x32_bf16(a1, b1, acc[1][1], 0, 0, 0);
        acc[1][2] = __builtin_amdgcn_mfma_f32_16x16x32_bf16(a1, b2, acc[1][2], 0, 0, 0);
        acc[1][3] = __builtin_amdgcn_mfma_f32_16x16x32_bf16(a1, b3, acc[1][3], 0, 0, 0);
    }

    // ---- epilogue: softplus-sum (bias folded into acc) ----
    float local = 0.0f;
#pragma unroll
    for (int i = 0; i < 2; ++i)
#pragma unroll
        for (int j = 0; j < 4; ++j) {
            local += softplus_f(acc[i][j].x);
            local += softplus_f(acc[i][j].y);
            local += softplus_f(acc[i][j].z);
            local += softplus_f(acc[i][j].w);
        }

    // ---- positive term: ex decoded from As (bf16), tail gathered fp32 ----
    if (doPos) {
        const short* exr = As + (tid - 192) * PITCH;
        const float4* tv = (const float4*)ptail;
        float d0 = 0.f, d1 = 0.f, d2 = 0.f, d3 = 0.f;
#pragma unroll
        for (int j = 0; j < 25; ++j) {
            const s4 e = *(const s4*)(exr + 4 * j);
            const float4 v = tv[j];
            d0 = fmaf(bf16_to_f(e.x), v.x, d0);
            d1 = fmaf(bf16_to_f(e.y), v.y, d1);
            d2 = fmaf(bf16_to_f(e.z), v.z, d2);
            d3 = fmaf(bf16_to_f(e.w), v.w, d3);
        }
        const float pos = ((d0 + d1) + (d2 + d3)) + pbias;
        local += softplus_f(-pos);
    }

    // ---- reduction ----
#pragma unroll
    for (int off = 32; off > 0; off >>= 1)
        local += __shfl_down(local, off, 64);

    __syncthreads();
    float* wsum = (float*)Bs;
    if (lane == 0) wsum[wave] = local;
    __syncthreads();
    if (tid == 0) {
        const float s = (wsum[0] + wsum[1]) + (wsum[2] + wsum[3]);
        atomicAdd(p.out, s * (1.0f / BATCH));
    }
}

extern "C" void kernel_launch(void* const* d_in, const int* in_sizes, int n_in,
                              void* d_out, int out_size, void* d_ws, size_t ws_size,
                              hipStream_t stream) {
    const float* user  = (const float*)d_in[0];
    const float* prod  = (const float*)d_in[1];
    const float* word  = (const float*)d_in[2];
    const float* brand = (const float*)d_in[3];
    const float* cat   = (const float*)d_in[4];
    const float* rprod = (const float*)d_in[5];

    Params p;
    p.rel_vecs   = (const float*)d_in[6];
    p.batch_idxs = (const int*)d_in[15];
    p.neg_idxs   = (const int*)d_in[16];
    p.out        = (float*)d_out;

    p.rel[0] = {user, prod,  (const float*)d_in[7],  0, 1};  // purchase
    p.rel[1] = {user, word,  (const float*)d_in[8],  0, 2};  // mentions
    p.rel[2] = {prod, word,  (const float*)d_in[9],  1, 2};  // describe
    p.rel[3] = {prod, brand, (const float*)d_in[10], 1, 3};  // produced
    p.rel[4] = {prod, cat,   (const float*)d_in[11], 1, 4};  // belongs
    p.rel[5] = {prod, rprod, (const float*)d_in[12], 1, 5};  // also_bought
    p.rel[6] = {prod, rprod, (const float*)d_in[13], 1, 6};  // also_viewed
    p.rel[7] = {prod, rprod, (const float*)d_in[14], 1, 7};  // together

    short* aws = (short*)d_ws;                       // 32768 * 136 shorts
    short* bws = aws + (size_t)32768 * PITCH;        // 2048 * 136 shorts

    hipMemsetAsync(d_out, 0, sizeof(float), stream);
    ke_prep<<<136, 256, 0, stream>>>(p, aws, bws);
    ke_main<<<1024, 256, 0, stream>>>(p, aws, bws);
}